// Round 1
// baseline (510.806 us; speedup 1.0000x reference)
//
#include <hip/hip_runtime.h>

// ---------------------------------------------------------------------------
// FP8Linear: out = (q8(x*sx) @ q8(W*sw)^T) / (sx*sw) + bias
// M=16384, K=2048, N=2048 (derived from in_sizes at launch)
// Pipeline: init -> amax(x) -> amax(W) -> scales -> quant(x) -> quant(W) -> GEMM
// GEMM follows the m97/m145-verified structure: 128x128 tile, BK=64,
// global_load_lds width=16, 16x16x32 fp8_fp8 MFMA, 4 waves x 4x4 acc tiles.
// ---------------------------------------------------------------------------

typedef __attribute__((ext_vector_type(4))) float floatx4;

#define FP8_MAX_F 448.0f

// --- async global->LDS, 16B per lane. LDS dest must be wave-uniform base +
// lane*16 (m104/m108); our staging layout satisfies this (lds = tid*16).
__device__ __forceinline__ void async_load16(const void* g, void* l) {
    __builtin_amdgcn_global_load_lds(
        (const __attribute__((address_space(1))) unsigned int*)g,
        (__attribute__((address_space(3))) unsigned int*)l,
        16, 0, 0);
}

// --- zero the two amax accumulators (ws is poisoned 0xAA before each call)
__global__ void init_kernel(unsigned int* amax) {
    if (threadIdx.x < 2) amax[threadIdx.x] = 0u;
}

// --- amax reduction: float4 grid-stride, wave shuffle, block LDS, atomicMax
// on uint bits (all values >= 0 so the bit pattern is order-preserving).
__global__ __launch_bounds__(256) void amax_kernel(const float* __restrict__ x,
                                                   long n4,
                                                   unsigned int* __restrict__ amax) {
    long i = (long)blockIdx.x * blockDim.x + threadIdx.x;
    long stride = (long)gridDim.x * blockDim.x;
    const float4* x4 = (const float4*)x;
    float m = 0.0f;
    for (long j = i; j < n4; j += stride) {
        float4 v = x4[j];
        m = fmaxf(m, fmaxf(fmaxf(fabsf(v.x), fabsf(v.y)),
                           fmaxf(fabsf(v.z), fabsf(v.w))));
    }
    #pragma unroll
    for (int off = 32; off > 0; off >>= 1)
        m = fmaxf(m, __shfl_down(m, off));
    __shared__ float wmax[4];
    int lane = threadIdx.x & 63, wid = threadIdx.x >> 6;
    if (lane == 0) wmax[wid] = m;
    __syncthreads();
    if (threadIdx.x == 0) {
        float b = fmaxf(fmaxf(wmax[0], wmax[1]), fmaxf(wmax[2], wmax[3]));
        atomicMax(amax, __float_as_uint(b));
    }
}

// --- replicate reference fp32 scale arithmetic exactly:
// scale = 448 / (amax + 1e-12) * 0.9
__global__ void scale_kernel(const unsigned int* __restrict__ amax,
                             float* __restrict__ scales) {
    if (threadIdx.x == 0) {
        float ax = __uint_as_float(amax[0]);
        float aw = __uint_as_float(amax[1]);
        float is = FP8_MAX_F / (ax + 1e-12f) * 0.9f;
        float ws = FP8_MAX_F / (aw + 1e-12f) * 0.9f;
        scales[0] = is;
        scales[1] = ws;
        scales[2] = 1.0f / (is * ws);
    }
}

// --- quantize: clamp(v*s, +-448) -> e4m3fn via HW cvt (RNE, OCP format).
// 4 floats -> 4 bytes per iteration (float4 in, u32 out).
__global__ __launch_bounds__(256) void quant_kernel(const float* __restrict__ x,
                                                    long n4,
                                                    const float* __restrict__ scale_p,
                                                    unsigned int* __restrict__ out) {
    float s = *scale_p;
    long i = (long)blockIdx.x * blockDim.x + threadIdx.x;
    long stride = (long)gridDim.x * blockDim.x;
    const float4* x4 = (const float4*)x;
    for (long j = i; j < n4; j += stride) {
        float4 v = x4[j];
        float a0 = fminf(fmaxf(v.x * s, -FP8_MAX_F), FP8_MAX_F);
        float a1 = fminf(fmaxf(v.y * s, -FP8_MAX_F), FP8_MAX_F);
        float a2 = fminf(fmaxf(v.z * s, -FP8_MAX_F), FP8_MAX_F);
        float a3 = fminf(fmaxf(v.w * s, -FP8_MAX_F), FP8_MAX_F);
        int p = __builtin_amdgcn_cvt_pk_fp8_f32(a0, a1, 0, false);
        p = __builtin_amdgcn_cvt_pk_fp8_f32(a2, a3, p, true);
        out[j] = (unsigned int)p;
    }
}

// --- GEMM: C[m,n] = sum_k A8[m,k]*W8[n,k]  (both K-contiguous = B^T form)
// epilogue: C = acc * rcp + bias[n]
#define BM 128
#define BN 128
#define BK 64

__global__ __launch_bounds__(256) void gemm_fp8(
    const unsigned char* __restrict__ A,  // [M,K] fp8
    const unsigned char* __restrict__ B,  // [N,K] fp8
    const float* __restrict__ bias,       // [N]
    const float* __restrict__ scales,     // scales[2] = 1/(sx*sw)
    float* __restrict__ C,                // [M,N] fp32
    int M, int N, int K) {
    __shared__ unsigned char As[BM * BK];  // 8 KB, row-major [128][64], no pad
    __shared__ unsigned char Bs[BN * BK];  // 8 KB

    const int t = threadIdx.x;
    const int lane = t & 63;
    const int w = t >> 6;            // wave 0..3
    const int bm = blockIdx.y * BM;
    const int bn = blockIdx.x * BN;
    const int wm = (w >> 1) * 64;    // wave's 64x64 quadrant
    const int wn = (w & 1) * 64;

    floatx4 acc[4][4] = {};

    // staging: thread t loads 16B; row = t/4 (4 threads * 16B = one 64B row)
    const int srow = t >> 2;
    const int scol = (t & 3) * 16;
    const unsigned char* gA0 = A + (long)(bm + srow) * K + scol;
    const unsigned char* gA1 = A + (long)(bm + 64 + srow) * K + scol;
    const unsigned char* gB0 = B + (long)(bn + srow) * K + scol;
    const unsigned char* gB1 = B + (long)(bn + 64 + srow) * K + scol;
    unsigned char* lA0 = As + t * 16;        // == srow*64 + scol
    unsigned char* lA1 = As + 4096 + t * 16;
    unsigned char* lB0 = Bs + t * 16;
    unsigned char* lB1 = Bs + 4096 + t * 16;

    // fragment addressing: 16x16x32 fp8 A/B layout: elem (l&15, (l>>4)*8 + j)
    const int fr = lane & 15;
    const int fk = (lane >> 4) * 8;

    for (int kt = 0; kt < K; kt += BK) {
        __syncthreads();  // previous iter's ds_reads done before overwrite
        async_load16(gA0 + kt, lA0);
        async_load16(gA1 + kt, lA1);
        async_load16(gB0 + kt, lB0);
        async_load16(gB1 + kt, lB1);
        __syncthreads();  // compiler emits vmcnt(0) drain before barrier

        long long a[2][4], b[2][4];
        #pragma unroll
        for (int kk = 0; kk < 2; kk++) {
            #pragma unroll
            for (int i = 0; i < 4; i++) {
                a[kk][i] = *(const long long*)(As + (wm + i * 16 + fr) * BK + kk * 32 + fk);
                b[kk][i] = *(const long long*)(Bs + (wn + i * 16 + fr) * BK + kk * 32 + fk);
            }
        }
        #pragma unroll
        for (int kk = 0; kk < 2; kk++)
            #pragma unroll
            for (int i = 0; i < 4; i++)
                #pragma unroll
                for (int j = 0; j < 4; j++)
                    acc[i][j] = __builtin_amdgcn_mfma_f32_16x16x32_fp8_fp8(
                        a[kk][i], b[kk][j], acc[i][j], 0, 0, 0);
    }

    // epilogue: C/D layout col = lane&15, row = (lane>>4)*4 + reg  (m89-verified,
    // dtype-independent on gfx950)
    const float rcp = scales[2];
    const int crow = bm + wm + (lane >> 4) * 4;
    const int ccol = bn + wn + fr;
    #pragma unroll
    for (int j = 0; j < 4; j++) {
        const int col = ccol + j * 16;
        const float bv = bias[col];
        #pragma unroll
        for (int i = 0; i < 4; i++) {
            const int row0 = crow + i * 16;
            #pragma unroll
            for (int r = 0; r < 4; r++)
                C[(long)(row0 + r) * N + col] = acc[i][j][r] * rcp + bv;
        }
    }
}

extern "C" void kernel_launch(void* const* d_in, const int* in_sizes, int n_in,
                              void* d_out, int out_size, void* d_ws, size_t ws_size,
                              hipStream_t stream) {
    const float* x = (const float*)d_in[0];    // [B,S,K] fp32
    const float* wt = (const float*)d_in[1];   // [N,K] fp32
    const float* bias = (const float*)d_in[2]; // [N] fp32
    float* out = (float*)d_out;                // [B*S, N] fp32

    const int xn = in_sizes[0];  // M*K
    const int wn = in_sizes[1];  // N*K
    const int N = in_sizes[2];
    const int K = wn / N;
    const int M = xn / K;

    unsigned char* wsb = (unsigned char*)d_ws;
    unsigned int* amax = (unsigned int*)wsb;          // 2 u32
    float* scales = (float*)(wsb + 16);               // 3 floats
    unsigned char* xq = wsb + 64;                     // M*K bytes
    unsigned char* wq = wsb + 64 + (size_t)xn;        // N*K bytes

    init_kernel<<<1, 64, 0, stream>>>(amax);
    amax_kernel<<<2048, 256, 0, stream>>>(x, (long)xn / 4, amax + 0);
    amax_kernel<<<512, 256, 0, stream>>>(wt, (long)wn / 4, amax + 1);
    scale_kernel<<<1, 64, 0, stream>>>(amax, scales);
    quant_kernel<<<2048, 256, 0, stream>>>(x, (long)xn / 4, scales + 0,
                                           (unsigned int*)xq);
    quant_kernel<<<512, 256, 0, stream>>>(wt, (long)wn / 4, scales + 1,
                                          (unsigned int*)wq);
    dim3 grid(N / BN, M / BM);
    gemm_fp8<<<grid, 256, 0, stream>>>(xq, wq, bias, scales, out, M, N, K);
}

// Round 2
// 365.681 us; speedup vs baseline: 1.3969x; 1.3969x over previous
//
#include <hip/hip_runtime.h>

// ---------------------------------------------------------------------------
// FP8Linear: out = (q8(x*sx) @ q8(W*sw)^T) / (sx*sw) + bias
// M=16384, K=2048, N=2048 (derived from in_sizes at launch)
// R2: GEMM upgraded to MX-scaled fp8 (mfma_scale 16x16x128, unit scales) with
// BK=128B tiles and a 16B-granular XOR swizzle on the global->LDS mapping to
// make both staging writes and fragment ds_read_b128s bank-conflict-free.
// Side passes fused: memset(amax) -> amax_both -> quant_both -> gemm.
// ---------------------------------------------------------------------------

typedef __attribute__((ext_vector_type(4))) float floatx4;
typedef __attribute__((ext_vector_type(4))) int intx4;
typedef __attribute__((ext_vector_type(8))) int intx8;

#define FP8_MAX_F 448.0f

__device__ __forceinline__ void async_load16(const void* g, void* l) {
    __builtin_amdgcn_global_load_lds(
        (const __attribute__((address_space(1))) unsigned int*)g,
        (__attribute__((address_space(3))) unsigned int*)l,
        16, 0, 0);
}

__device__ __forceinline__ float scale_from_amax(unsigned int bits) {
    // must be the exact fp32 op sequence everywhere it is recomputed
    return FP8_MAX_F / (__uint_as_float(bits) + 1e-12f) * 0.9f;
}

// --- fused amax over x (blocks [0,nbx)) and w (blocks [nbx, grid)).
// atomicMax on uint bits: all values >= 0 so bit pattern is order-preserving.
__global__ __launch_bounds__(256) void amax_both(const float* __restrict__ x,
                                                 long xn4,
                                                 const float* __restrict__ w,
                                                 long wn4, int nbx,
                                                 unsigned int* __restrict__ amax) {
    const float4* src;
    long n4, bid, nblk;
    unsigned int* dst;
    if (blockIdx.x < (unsigned)nbx) {
        src = (const float4*)x; n4 = xn4; dst = amax;     bid = blockIdx.x;       nblk = nbx;
    } else {
        src = (const float4*)w; n4 = wn4; dst = amax + 1; bid = blockIdx.x - nbx; nblk = gridDim.x - nbx;
    }
    long i = bid * blockDim.x + threadIdx.x;
    long stride = nblk * blockDim.x;
    float m = 0.0f;
    for (long j = i; j < n4; j += stride) {
        float4 v = src[j];
        m = fmaxf(m, fmaxf(fmaxf(fabsf(v.x), fabsf(v.y)),
                           fmaxf(fabsf(v.z), fabsf(v.w))));
    }
    #pragma unroll
    for (int off = 32; off > 0; off >>= 1)
        m = fmaxf(m, __shfl_down(m, off));
    __shared__ float wmax[4];
    int lane = threadIdx.x & 63, wid = threadIdx.x >> 6;
    if (lane == 0) wmax[wid] = m;
    __syncthreads();
    if (threadIdx.x == 0) {
        float b = fmaxf(fmaxf(wmax[0], wmax[1]), fmaxf(wmax[2], wmax[3]));
        atomicMax(dst, __float_as_uint(b));
    }
}

// --- fused quantize: clamp(v*s, +-448) -> e4m3fn via HW cvt (RNE, OCP).
__global__ __launch_bounds__(256) void quant_both(const float* __restrict__ x,
                                                  long xn4,
                                                  const float* __restrict__ w,
                                                  long wn4, int nbx,
                                                  const unsigned int* __restrict__ amax,
                                                  unsigned int* __restrict__ xq,
                                                  unsigned int* __restrict__ wq) {
    const float4* src;
    long n4, bid, nblk;
    unsigned int* dst;
    float s;
    if (blockIdx.x < (unsigned)nbx) {
        src = (const float4*)x; n4 = xn4; dst = xq; bid = blockIdx.x;       nblk = nbx;
        s = scale_from_amax(amax[0]);
    } else {
        src = (const float4*)w; n4 = wn4; dst = wq; bid = blockIdx.x - nbx; nblk = gridDim.x - nbx;
        s = scale_from_amax(amax[1]);
    }
    long i = bid * blockDim.x + threadIdx.x;
    long stride = nblk * blockDim.x;
    for (long j = i; j < n4; j += stride) {
        float4 v = src[j];
        float a0 = fminf(fmaxf(v.x * s, -FP8_MAX_F), FP8_MAX_F);
        float a1 = fminf(fmaxf(v.y * s, -FP8_MAX_F), FP8_MAX_F);
        float a2 = fminf(fmaxf(v.z * s, -FP8_MAX_F), FP8_MAX_F);
        float a3 = fminf(fmaxf(v.w * s, -FP8_MAX_F), FP8_MAX_F);
        int p = __builtin_amdgcn_cvt_pk_fp8_f32(a0, a1, 0, false);
        p = __builtin_amdgcn_cvt_pk_fp8_f32(a2, a3, p, true);
        dst[j] = (unsigned int)p;
    }
}

// --- GEMM: C[m,n] = sum_k A8[m,k]*W8[n,k]; epilogue C = acc*rcp + bias[n]
// 128x128 tile, BK=128 bytes, 4 waves x 4x4 tiles of 16x16x128 scaled-fp8 MFMA.
// LDS layout XOR-swizzled at 16B granularity: LDS[r][b] = G[r][b ^ (r&7)].
#define BM 128
#define BN 128
#define BKB 128

__global__ __launch_bounds__(256, 3) void gemm_fp8mx(
    const unsigned char* __restrict__ A,  // [M,K] fp8
    const unsigned char* __restrict__ B,  // [N,K] fp8
    const float* __restrict__ bias,       // [N]
    const unsigned int* __restrict__ amax,
    float* __restrict__ C,                // [M,N] fp32
    int M, int N, int K) {
    __shared__ __align__(16) unsigned char As[BM * BKB];  // 16 KB
    __shared__ __align__(16) unsigned char Bs[BN * BKB];  // 16 KB

    const int t = threadIdx.x;
    const int lane = t & 63;
    const int w = t >> 6;
    const int bm = blockIdx.y * BM;
    const int bn = blockIdx.x * BN;
    const int wm = (w >> 1) * 64;
    const int wn = (w & 1) * 64;

    floatx4 acc[4][4] = {};

    // staging: thread t -> LDS linear slot t*16 == (row = t>>3, blk = t&7);
    // load the XOR-swizzled global 16B block so LDS[r][b] = G[r][b^(r&7)]
    const int srow = t >> 3;                       // 0..31
    const int gcol = ((t & 7) ^ (srow & 7)) * 16;  // swizzled 16B block
    const unsigned char* gA = A + (long)(bm + srow) * K + gcol;
    const unsigned char* gB = B + (long)(bn + srow) * K + gcol;
    unsigned char* lA = As + t * 16;
    unsigned char* lB = Bs + t * 16;

    // fragment addressing: 16x16x128 f8f6f4 A/B: lane holds
    // elem (l&15, (l>>4)*32 + j), j=0..31 -> two swizzled 16B reads
    const int fr = lane & 15;
    const int sw = fr & 7;
    const int b0 = (lane >> 4) * 2;
    const int off0 = (b0 ^ sw) * 16;
    const int off1 = ((b0 + 1) ^ sw) * 16;
    const int rowA = (wm + fr) * BKB;
    const int rowB = (wn + fr) * BKB;

    for (int kt = 0; kt < K; kt += BKB) {
        __syncthreads();
        #pragma unroll
        for (int c = 0; c < 4; c++) {
            async_load16(gA + (long)c * 32 * K + kt, lA + c * 4096);
            async_load16(gB + (long)c * 32 * K + kt, lB + c * 4096);
        }
        __syncthreads();

        intx8 bfrag[4];
        #pragma unroll
        for (int j = 0; j < 4; j++) {
            intx4 lo = *(const intx4*)(Bs + rowB + j * 2048 + off0);
            intx4 hi = *(const intx4*)(Bs + rowB + j * 2048 + off1);
            bfrag[j] = (intx8){lo.x, lo.y, lo.z, lo.w, hi.x, hi.y, hi.z, hi.w};
        }
        #pragma unroll
        for (int i = 0; i < 4; i++) {
            intx4 lo = *(const intx4*)(As + rowA + i * 2048 + off0);
            intx4 hi = *(const intx4*)(As + rowA + i * 2048 + off1);
            intx8 afrag = (intx8){lo.x, lo.y, lo.z, lo.w, hi.x, hi.y, hi.z, hi.w};
            #pragma unroll
            for (int j = 0; j < 4; j++)
                acc[i][j] = __builtin_amdgcn_mfma_scale_f32_16x16x128_f8f6f4(
                    afrag, bfrag[j], acc[i][j],
                    /*cbsz=fp8*/ 0, /*blgp=fp8*/ 0,
                    0, 0x7f7f7f7f, 0, 0x7f7f7f7f);  // unit e8m0 scales
        }
    }

    // epilogue: C/D layout col = lane&15, row = (lane>>4)*4 + reg (16x16 shapes)
    const float is = scale_from_amax(amax[0]);
    const float ws = scale_from_amax(amax[1]);
    const float rcp = 1.0f / (is * ws);
    const int crow = bm + wm + (lane >> 4) * 4;
    const int ccol = bn + wn + fr;
    #pragma unroll
    for (int j = 0; j < 4; j++) {
        const int col = ccol + j * 16;
        const float bv = bias[col];
        #pragma unroll
        for (int i = 0; i < 4; i++) {
            const int row0 = crow + i * 16;
            #pragma unroll
            for (int r = 0; r < 4; r++)
                C[(long)(row0 + r) * N + col] = acc[i][j][r] * rcp + bv;
        }
    }
}

extern "C" void kernel_launch(void* const* d_in, const int* in_sizes, int n_in,
                              void* d_out, int out_size, void* d_ws, size_t ws_size,
                              hipStream_t stream) {
    const float* x = (const float*)d_in[0];    // [B,S,K] fp32
    const float* wt = (const float*)d_in[1];   // [N,K] fp32
    const float* bias = (const float*)d_in[2]; // [N] fp32
    float* out = (float*)d_out;                // [B*S, N] fp32

    const int xn = in_sizes[0];  // M*K
    const int wn = in_sizes[1];  // N*K
    const int N = in_sizes[2];
    const int K = wn / N;
    const int M = xn / K;

    unsigned char* wsb = (unsigned char*)d_ws;
    unsigned int* amax = (unsigned int*)wsb;   // 2 u32
    unsigned char* xq = wsb + 64;              // M*K bytes
    unsigned char* wq = wsb + 64 + (size_t)xn; // N*K bytes

    hipMemsetAsync(amax, 0, 8, stream);
    amax_both<<<2560, 256, 0, stream>>>(x, (long)xn / 4, wt, (long)wn / 4, 2048, amax);
    quant_both<<<2560, 256, 0, stream>>>(x, (long)xn / 4, wt, (long)wn / 4, 2048,
                                         amax, (unsigned int*)xq, (unsigned int*)wq);
    dim3 grid(N / BN, M / BM);
    gemm_fp8mx<<<grid, 256, 0, stream>>>(xq, wq, bias, amax, out, M, N, K);
}